// Round 4
// baseline (4282.806 us; speedup 1.0000x reference)
//
#include <hip/hip_runtime.h>

#define SDIM 8192
#define RAD  256     // WINDOW_SIZE/2
#define GTOK 64
#define KSEL 8
#define CAP  768
#define THRESH 2.2f  // P(N(0,1)>2.2)=1.39% -> ~114 candidates/row; [8,768] is >30 sigma safe

// Single-pass: read row -> top-8 -> publish count -> mask write -> decoupled
// lookback for exclusive offset -> col_indices write. One kernel, one launch.
__global__ __launch_bounds__(256) void onepass_kernel(const float* __restrict__ scores,
                                                      unsigned long long* __restrict__ fv,
                                                      float* __restrict__ mask_out,
                                                      float* __restrict__ off_out,
                                                      float* __restrict__ col_out,
                                                      float* __restrict__ cnt_out,
                                                      float* __restrict__ sp_out) {
    __shared__ float cand_v[CAP];
    __shared__ int   cand_i[CAP];
    __shared__ int   top8[KSEL];
    __shared__ int   cs[256];
    __shared__ int   cnt;
    __shared__ int   s_off;
    const int row = blockIdx.x;
    const int t   = threadIdx.x;
    if (t == 0) cnt = 0;
    __syncthreads();

    // ---- phase 1: coalesced row read + threshold filter into LDS candidates
    const float4* rowp = reinterpret_cast<const float4*>(scores + (size_t)row * SDIM);
#pragma unroll
    for (int k = 0; k < 8; k++) {
        int f4 = t + k * 256;
        float4 d = rowp[f4];
        int jb = f4 * 4;
        if (d.x > THRESH) { int p = atomicAdd(&cnt, 1); if (p < CAP) { cand_v[p] = d.x; cand_i[p] = jb;     } }
        if (d.y > THRESH) { int p = atomicAdd(&cnt, 1); if (p < CAP) { cand_v[p] = d.y; cand_i[p] = jb + 1; } }
        if (d.z > THRESH) { int p = atomicAdd(&cnt, 1); if (p < CAP) { cand_v[p] = d.z; cand_i[p] = jb + 2; } }
        if (d.w > THRESH) { int p = atomicAdd(&cnt, 1); if (p < CAP) { cand_v[p] = d.w; cand_i[p] = jb + 3; } }
    }
    __syncthreads();

    const int n = cnt;
    const bool bad = (n < KSEL || n > CAP);   // block-uniform

    // ---- phase 2: exact top-8 (argmax rounds, tie-break to lower index)
    if (!bad) {
        if (t < 64) {
            for (int round = 0; round < KSEL; round++) {
                float bv = -INFINITY; int bi = 0x7fffffff;
                for (int c = t; c < n; c += 64) {
                    float val = cand_v[c]; int id = cand_i[c];
                    if (val > bv || (val == bv && id < bi)) { bv = val; bi = id; }
                }
#pragma unroll
                for (int s = 32; s > 0; s >>= 1) {
                    float ov = __shfl_down(bv, s);
                    int   oi = __shfl_down(bi, s);
                    if (ov > bv || (ov == bv && oi < bi)) { bv = ov; bi = oi; }
                }
                bi = __shfl(bi, 0);
                for (int c = t; c < n; c += 64) if (cand_i[c] == bi) cand_v[c] = -INFINITY;
                if (t == 0) top8[round] = bi;
            }
        }
    } else {
        // exact inline fallback (never fires for this input; data-independence
        // guard): block-wide 8-round argmax, re-reading the L2-hot row
        for (int round = 0; round < KSEL; round++) {
            float bv = -INFINITY; int bi = 0x7fffffff;
            for (int k = 0; k < 8; k++) {
                int f4 = t + k * 256;
                float4 d = rowp[f4];
                float vals[4] = {d.x, d.y, d.z, d.w};
                int jb = f4 * 4;
                for (int e = 0; e < 4; e++) {
                    int j = jb + e;
                    bool used = false;
                    for (int q = 0; q < round; q++) used = used || (top8[q] == j);
                    if (!used && vals[e] > bv) { bv = vals[e]; bi = j; }  // ascending j -> ties to lowest
                }
            }
            cand_v[t] = bv; cand_i[t] = bi;
            __syncthreads();
            if (t < 64) {
                for (int c = t + 64; c < 256; c += 64) {
                    float vv = cand_v[c]; int ii = cand_i[c];
                    if (vv > bv || (vv == bv && ii < bi)) { bv = vv; bi = ii; }
                }
#pragma unroll
                for (int s = 32; s > 0; s >>= 1) {
                    float ov = __shfl_down(bv, s);
                    int   oi = __shfl_down(bi, s);
                    if (ov > bv || (ov == bv && oi < bi)) { bv = ov; bi = oi; }
                }
                if (t == 0) top8[round] = bi;
            }
            __syncthreads();
        }
    }
    __syncthreads();

    int wlo = row - RAD; if (wlo < 0) wlo = 0;
    int whi = row + RAD; if (whi > SDIM - 1) whi = SDIM - 1;
    const unsigned wspan = (unsigned)(whi - wlo);
    const bool full = row < GTOK;

    int r[KSEL];
#pragma unroll
    for (int q = 0; q < KSEL; q++) r[q] = top8[q];

    // ---- phase 3a: publish this row's count ASAP (unblocks successors)
    int c_row;
    {
        if (full) c_row = SDIM;
        else {
            c_row = (whi - wlo + 1) + (wlo < GTOK ? wlo : GTOK);
#pragma unroll
            for (int q = 0; q < KSEL; q++)
                if (r[q] >= GTOK && (r[q] < wlo || r[q] > whi)) c_row++;
        }
        if (t == 0) {
            unsigned long long w = (1ull << 62) | (unsigned long long)(unsigned)c_row;
            __hip_atomic_store(&fv[row], w, __ATOMIC_RELEASE, __HIP_MEMORY_SCOPE_AGENT);
        }
    }

    // ---- phase 3b: mask row write (overlaps predecessors' publishing)
    float4* mrow = reinterpret_cast<float4*>(mask_out + (size_t)row * SDIM);
#pragma unroll
    for (int k = 0; k < 8; k++) {
        int f4 = t + k * 256;
        int jb = f4 * 4;
        float4 o;
        float* op = &o.x;
#pragma unroll
        for (int e = 0; e < 4; e++) {
            int j = jb + e;
            bool b = full || (j < GTOK) || ((unsigned)(j - wlo) <= wspan);
#pragma unroll
            for (int q = 0; q < KSEL; q++) b = b || (j == r[q]);
            op[e] = b ? 1.0f : 0.0f;
        }
        mrow[f4] = o;
    }

    // ---- phase 4: decoupled lookback -> exclusive offset
    if (t == 0) {
        long long run = 0;
        int p = row - 1;
        while (p >= 0) {
            unsigned long long w;
            for (;;) {
                w = __hip_atomic_load(&fv[p], __ATOMIC_ACQUIRE, __HIP_MEMORY_SCOPE_AGENT);
                if ((w >> 62) != 0ull) break;
                __builtin_amdgcn_s_sleep(1);
            }
            run += (long long)(w & 0xFFFFFFFFull);
            if ((w >> 62) == 2ull) break;
            p--;
        }
        unsigned long long w = (2ull << 62) | (unsigned long long)(run + c_row);
        __hip_atomic_store(&fv[row], w, __ATOMIC_RELEASE, __HIP_MEMORY_SCOPE_AGENT);
        s_off = (int)run;
        off_out[row] = (float)run;
        cnt_out[row] = (float)c_row;
        if (row == SDIM - 1) {
            off_out[SDIM] = (float)(run + c_row);
            sp_out[0] = (float)(run + c_row) / 67108864.0f;   // < 2^24 -> exact
        }
    }
    __syncthreads();
    const int offset = s_off;

    // ---- phase 5: col_indices (bitmask + block scan, ascending j)
    const int jb = t * 32;
    unsigned int bm;
    if (full || jb + 31 < GTOK) {
        bm = ~0u;
    } else {
        bm = 0u;
        int lo = wlo > jb ? wlo : jb;
        int hi = whi < jb + 31 ? whi : jb + 31;
        if (lo <= hi) {
            int a = lo - jb, z = hi - jb;
            unsigned hiM = (z == 31) ? ~0u : ((1u << (z + 1)) - 1u);
            unsigned loM = (1u << a) - 1u;
            bm = hiM & ~loM;
        }
#pragma unroll
        for (int q = 0; q < KSEL; q++)
            if ((r[q] >> 5) == t) bm |= 1u << (r[q] & 31);
    }
    cs[t] = __popc(bm);
    __syncthreads();
    for (int d = 1; d < 256; d <<= 1) {
        int add = (t >= d) ? cs[t - d] : 0;
        __syncthreads();
        cs[t] += add;
        __syncthreads();
    }
    int pos = offset + ((t == 0) ? 0 : cs[t - 1]);
    for (int e = 0; e < 32; e++) {
        if ((bm >> e) & 1u) col_out[pos++] = (float)(jb + e);
    }
}

extern "C" void kernel_launch(void* const* d_in, const int* in_sizes, int n_in,
                              void* d_out, int out_size, void* d_ws, size_t ws_size,
                              hipStream_t stream) {
    const float* scores = (const float*)d_in[1];   // rand_scores [S,S] f32

    float* out_f    = (float*)d_out;
    float* mask_out = out_f;                                   // S*S
    float* off_out  = out_f + (size_t)SDIM * SDIM;             // S+1
    float* col_out  = off_out + (SDIM + 1);                    // TC
    const long long TC = (long long)out_size
                       - ((long long)SDIM * SDIM + (SDIM + 1) + SDIM + 1);
    float* cnt_out = col_out + TC;                             // S
    float* sp_out  = cnt_out + SDIM;                           // 1

    unsigned long long* fv = (unsigned long long*)d_ws;        // S lookback words

    // ws is NOT re-poisoned between replays -> reset lookback state every call
    hipMemsetAsync(fv, 0, SDIM * sizeof(unsigned long long), stream);
    onepass_kernel<<<SDIM, 256, 0, stream>>>(scores, fv, mask_out, off_out,
                                             col_out, cnt_out, sp_out);
}

// Round 5
// 164.933 us; speedup vs baseline: 25.9669x; 25.9669x over previous
//
#include <hip/hip_runtime.h>

#define SDIM 8192
#define RAD  256     // WINDOW_SIZE/2
#define GTOK 64
#define KSEL 8
#define CAP  768
#define THRESH 2.2f  // P(N(0,1)>2.2)=1.39% -> ~114 candidates/row; [8,768] is >30 sigma safe

// ---- kernel A: read row -> threshold top-8 (exact inline fallback) -> count
// (+ 64-row group partial via atomic) -> mask row write
__global__ __launch_bounds__(256) void fused_kernel(const float* __restrict__ scores,
                                                    int* __restrict__ rand_idx,
                                                    int* __restrict__ counts,
                                                    int* __restrict__ partials,
                                                    float* __restrict__ cnt_out,
                                                    float* __restrict__ mask_out) {
    __shared__ float cand_v[CAP];
    __shared__ int   cand_i[CAP];
    __shared__ int   top8[KSEL];
    __shared__ int   cnt;
    const int row = blockIdx.x;
    const int t   = threadIdx.x;
    if (t == 0) cnt = 0;
    __syncthreads();

    // phase 1: coalesced row read + threshold filter
    const float4* rowp = reinterpret_cast<const float4*>(scores + (size_t)row * SDIM);
    float4 d[8];
#pragma unroll
    for (int k = 0; k < 8; k++) d[k] = rowp[t + k * 256];
#pragma unroll
    for (int k = 0; k < 8; k++) {
        int jb = (t + k * 256) * 4;
        if (d[k].x > THRESH) { int p = atomicAdd(&cnt, 1); if (p < CAP) { cand_v[p] = d[k].x; cand_i[p] = jb;     } }
        if (d[k].y > THRESH) { int p = atomicAdd(&cnt, 1); if (p < CAP) { cand_v[p] = d[k].y; cand_i[p] = jb + 1; } }
        if (d[k].z > THRESH) { int p = atomicAdd(&cnt, 1); if (p < CAP) { cand_v[p] = d[k].z; cand_i[p] = jb + 2; } }
        if (d[k].w > THRESH) { int p = atomicAdd(&cnt, 1); if (p < CAP) { cand_v[p] = d[k].w; cand_i[p] = jb + 3; } }
    }
    __syncthreads();

    const int n = cnt;
    const bool bad = (n < KSEL || n > CAP);   // block-uniform

    // phase 2: exact top-8 of candidate set (argmax rounds, ties -> lower idx)
    if (!bad) {
        if (t < 64) {
            for (int round = 0; round < KSEL; round++) {
                float bv = -INFINITY; int bi = 0x7fffffff;
                for (int c = t; c < n; c += 64) {
                    float val = cand_v[c]; int id = cand_i[c];
                    if (val > bv || (val == bv && id < bi)) { bv = val; bi = id; }
                }
#pragma unroll
                for (int s = 32; s > 0; s >>= 1) {
                    float ov = __shfl_down(bv, s);
                    int   oi = __shfl_down(bi, s);
                    if (ov > bv || (ov == bv && oi < bi)) { bv = ov; bi = oi; }
                }
                bi = __shfl(bi, 0);
                for (int c = t; c < n; c += 64) if (cand_i[c] == bi) cand_v[c] = -INFINITY;
                if (t == 0) top8[round] = bi;
            }
        }
    } else {
        // exact inline fallback (data-independence guard; never fires for the
        // fixed input): block-wide 8-round argmax over the L2-hot row
        for (int round = 0; round < KSEL; round++) {
            float bv = -INFINITY; int bi = 0x7fffffff;
            for (int k = 0; k < 8; k++) {
                int f4 = t + k * 256;
                float vals[4] = {d[k].x, d[k].y, d[k].z, d[k].w};
                int jb = f4 * 4;
                for (int e = 0; e < 4; e++) {
                    int j = jb + e;
                    bool used = false;
                    for (int q = 0; q < round; q++) used = used || (top8[q] == j);
                    if (!used && vals[e] > bv) { bv = vals[e]; bi = j; }
                }
            }
            cand_v[t] = bv; cand_i[t] = bi;
            __syncthreads();
            if (t < 64) {
                for (int c = t + 64; c < 256; c += 64) {
                    float vv = cand_v[c]; int ii = cand_i[c];
                    if (vv > bv || (vv == bv && ii < bi)) { bv = vv; bi = ii; }
                }
#pragma unroll
                for (int s = 32; s > 0; s >>= 1) {
                    float ov = __shfl_down(bv, s);
                    int   oi = __shfl_down(bi, s);
                    if (ov > bv || (ov == bv && oi < bi)) { bv = ov; bi = oi; }
                }
                if (t == 0) top8[round] = bi;
            }
            __syncthreads();
        }
    }
    __syncthreads();

    int wlo = row - RAD; if (wlo < 0) wlo = 0;
    int whi = row + RAD; if (whi > SDIM - 1) whi = SDIM - 1;
    const unsigned wspan = (unsigned)(whi - wlo);
    const bool full = row < GTOK;

    int r[KSEL];
#pragma unroll
    for (int q = 0; q < KSEL; q++) r[q] = top8[q];

    // phase 3: analytic count + group partial
    if (t == 0) {
        int c;
        if (full) c = SDIM;
        else {
            c = (whi - wlo + 1) + (wlo < GTOK ? wlo : GTOK);
#pragma unroll
            for (int q = 0; q < KSEL; q++)
                if (r[q] >= GTOK && (r[q] < wlo || r[q] > whi)) c++;
        }
        counts[row] = c;
        cnt_out[row] = (float)c;
        atomicAdd(&partials[row >> 6], c);
#pragma unroll
        for (int q = 0; q < KSEL; q++) rand_idx[row * KSEL + q] = r[q];
    }

    // phase 4: mask row write, span early-out (most float4 spans uniform zero)
    float4* mrow = reinterpret_cast<float4*>(mask_out + (size_t)row * SDIM);
    if (full) {
        const float4 ones = {1.0f, 1.0f, 1.0f, 1.0f};
#pragma unroll
        for (int k = 0; k < 8; k++) mrow[t + k * 256] = ones;
    } else {
#pragma unroll
        for (int k = 0; k < 8; k++) {
            int f4 = t + k * 256;
            int jb = f4 * 4;
            bool winHit = (jb <= whi) && (jb + 3 >= wlo);
            bool glbHit = jb < GTOK;
            bool rndHit = false;
#pragma unroll
            for (int q = 0; q < KSEL; q++) rndHit = rndHit || ((unsigned)(r[q] - jb) <= 3u);
            float4 o;
            if (!(winHit || glbHit || rndHit)) {
                o = {0.0f, 0.0f, 0.0f, 0.0f};
            } else {
                float* op = &o.x;
#pragma unroll
                for (int e = 0; e < 4; e++) {
                    int j = jb + e;
                    bool b = (j < GTOK) || ((unsigned)(j - wlo) <= wspan);
#pragma unroll
                    for (int q = 0; q < KSEL; q++) b = b || (j == r[q]);
                    op[e] = b ? 1.0f : 0.0f;
                }
            }
            mrow[f4] = o;
        }
    }
}

// ---- kernel B: per-row offset from group partials + in-group counts (L2-hot),
// then offsets/cols/sparsity
__global__ __launch_bounds__(256) void col_kernel(const int* __restrict__ rand_idx,
                                                  const int* __restrict__ counts,
                                                  const int* __restrict__ partials,
                                                  float* __restrict__ off_out,
                                                  float* __restrict__ col_out,
                                                  float* __restrict__ sp_out) {
    __shared__ int cs[256];
    __shared__ int s_off;
    const int row = blockIdx.x;
    const int t   = threadIdx.x;

    // offset = sum(partials[0..g-1]) + sum(counts[g*64..row-1])
    if (t < 64) {
        const int g = row >> 6;
        int acc = 0;
        for (int h = t; h < g; h += 64) acc += partials[h];
        for (int i = (g << 6) + t; i < row; i += 64) acc += counts[i];
#pragma unroll
        for (int s = 32; s > 0; s >>= 1) acc += __shfl_down(acc, s);
        if (t == 0) s_off = acc;
    }
    __syncthreads();
    const int offset = s_off;

    int r[KSEL];
#pragma unroll
    for (int q = 0; q < KSEL; q++) r[q] = rand_idx[row * KSEL + q];
    const bool full = row < GTOK;
    int wlo = row - RAD; if (wlo < 0) wlo = 0;
    int whi = row + RAD; if (whi > SDIM - 1) whi = SDIM - 1;

    const int jb = t * 32;
    unsigned int bm;
    if (full || jb + 31 < GTOK) {
        bm = ~0u;
    } else {
        bm = 0u;
        int lo = wlo > jb ? wlo : jb;
        int hi = whi < jb + 31 ? whi : jb + 31;
        if (lo <= hi) {
            int a = lo - jb, z = hi - jb;
            unsigned hiM = (z == 31) ? ~0u : ((1u << (z + 1)) - 1u);
            unsigned loM = (1u << a) - 1u;
            bm = hiM & ~loM;
        }
#pragma unroll
        for (int q = 0; q < KSEL; q++)
            if ((r[q] >> 5) == t) bm |= 1u << (r[q] & 31);
    }
    cs[t] = __popc(bm);
    __syncthreads();
    for (int d = 1; d < 256; d <<= 1) {
        int add = (t >= d) ? cs[t - d] : 0;
        __syncthreads();
        cs[t] += add;
        __syncthreads();
    }
    int pos = offset + ((t == 0) ? 0 : cs[t - 1]);
    for (int e = 0; e < 32; e++) {
        if ((bm >> e) & 1u) col_out[pos++] = (float)(jb + e);
    }

    if (t == 0) {
        off_out[row] = (float)offset;
        if (row == SDIM - 1) {
            int total = offset + counts[row];
            off_out[SDIM] = (float)total;
            sp_out[0] = (float)total / 67108864.0f;   // < 2^24 -> exact
        }
    }
}

extern "C" void kernel_launch(void* const* d_in, const int* in_sizes, int n_in,
                              void* d_out, int out_size, void* d_ws, size_t ws_size,
                              hipStream_t stream) {
    const float* scores = (const float*)d_in[1];   // rand_scores [S,S] f32

    float* out_f    = (float*)d_out;
    float* mask_out = out_f;                                   // S*S
    float* off_out  = out_f + (size_t)SDIM * SDIM;             // S+1
    float* col_out  = off_out + (SDIM + 1);                    // TC
    const long long TC = (long long)out_size
                       - ((long long)SDIM * SDIM + (SDIM + 1) + SDIM + 1);
    float* cnt_out = col_out + TC;                             // S
    float* sp_out  = cnt_out + SDIM;                           // 1

    int* rand_idx = (int*)d_ws;                  // S*K ints
    int* counts   = rand_idx + SDIM * KSEL;      // S ints
    int* partials = counts + SDIM;               // 128 ints

    // ws is NOT re-poisoned between replays -> reset group partials every call
    hipMemsetAsync(partials, 0, 128 * sizeof(int), stream);
    fused_kernel<<<SDIM, 256, 0, stream>>>(scores, rand_idx, counts, partials,
                                           cnt_out, mask_out);
    col_kernel<<<SDIM, 256, 0, stream>>>(rand_idx, counts, partials,
                                         off_out, col_out, sp_out);
}

// Round 6
// 155.399 us; speedup vs baseline: 27.5600x; 1.0614x over previous
//
#include <hip/hip_runtime.h>

#define SDIM 8192
#define RAD  256     // WINDOW_SIZE/2
#define GTOK 64
#define KSEL 8
#define CAP  768
#define THRESH 2.2f  // P(N(0,1)>2.2)=1.39% -> ~114 candidates/row; [8,768] is >30 sigma safe

// ---- kernel A: issue row loads -> write band/global mask row (independent of
// loads) -> threshold filter -> wave-0 top-8 -> t0 fixes up <=8 random mask
// cells + count + group partial. Selection is OFF the 524 MB critical path.
__global__ __launch_bounds__(256) void pass1_kernel(const float* __restrict__ scores,
                                                    int* __restrict__ rand_idx,
                                                    int* __restrict__ counts,
                                                    int* __restrict__ partials,
                                                    float* __restrict__ cnt_out,
                                                    float* __restrict__ mask_out) {
    __shared__ float cand_v[CAP];
    __shared__ int   cand_i[CAP];
    __shared__ int   top8[KSEL];
    __shared__ int   cnt;
    const int row = blockIdx.x;
    const int t   = threadIdx.x;
    if (t == 0) cnt = 0;
    __syncthreads();

    // issue all row loads first (8 outstanding float4/thread, coalesced)
    const float4* rowp = reinterpret_cast<const float4*>(scores + (size_t)row * SDIM);
    float4 d[8];
#pragma unroll
    for (int k = 0; k < 8; k++) d[k] = rowp[t + k * 256];

    // band/global mask row write — no dependency on the loads above; the
    // 32 KB store stream overlaps the 32 KB load latency
    int wlo = row - RAD; if (wlo < 0) wlo = 0;
    int whi = row + RAD; if (whi > SDIM - 1) whi = SDIM - 1;
    const unsigned wspan = (unsigned)(whi - wlo);
    const bool full = row < GTOK;
    float4* mrow = reinterpret_cast<float4*>(mask_out + (size_t)row * SDIM);
#pragma unroll
    for (int k = 0; k < 8; k++) {
        int f4 = t + k * 256;
        int jb = f4 * 4;
        float4 o; float* op = &o.x;
#pragma unroll
        for (int e = 0; e < 4; e++) {
            int j = jb + e;
            op[e] = (full || (j < GTOK) || ((unsigned)(j - wlo) <= wspan)) ? 1.0f : 0.0f;
        }
        mrow[f4] = o;
    }

    // threshold filter into LDS candidates (consumes d, which then dies)
#pragma unroll
    for (int k = 0; k < 8; k++) {
        int jb = (t + k * 256) * 4;
        if (d[k].x > THRESH) { int p = atomicAdd(&cnt, 1); if (p < CAP) { cand_v[p] = d[k].x; cand_i[p] = jb;     } }
        if (d[k].y > THRESH) { int p = atomicAdd(&cnt, 1); if (p < CAP) { cand_v[p] = d[k].y; cand_i[p] = jb + 1; } }
        if (d[k].z > THRESH) { int p = atomicAdd(&cnt, 1); if (p < CAP) { cand_v[p] = d[k].z; cand_i[p] = jb + 2; } }
        if (d[k].w > THRESH) { int p = atomicAdd(&cnt, 1); if (p < CAP) { cand_v[p] = d[k].w; cand_i[p] = jb + 3; } }
    }
    __syncthreads();   // also drains every wave's mask stores (vmcnt(0) before barrier)

    const int n = cnt;
    const bool bad = (n < KSEL || n > CAP);   // block-uniform

    if (!bad) {
        // wave-0 exact top-8 of candidate set (argmax rounds, ties -> lower idx)
        if (t < 64) {
            for (int round = 0; round < KSEL; round++) {
                float bv = -INFINITY; int bi = 0x7fffffff;
                for (int c = t; c < n; c += 64) {
                    float val = cand_v[c]; int id = cand_i[c];
                    if (val > bv || (val == bv && id < bi)) { bv = val; bi = id; }
                }
#pragma unroll
                for (int s = 32; s > 0; s >>= 1) {
                    float ov = __shfl_down(bv, s);
                    int   oi = __shfl_down(bi, s);
                    if (ov > bv || (ov == bv && oi < bi)) { bv = ov; bi = oi; }
                }
                bi = __shfl(bi, 0);
                for (int c = t; c < n; c += 64) if (cand_i[c] == bi) cand_v[c] = -INFINITY;
                if (t == 0) top8[round] = bi;
            }
        }
    } else {
        // exact inline fallback (data-independence guard; never fires for the
        // fixed input). Reloads the L2-hot row so d[] stays dead here.
        for (int round = 0; round < KSEL; round++) {
            float bv = -INFINITY; int bi = 0x7fffffff;
            for (int k = 0; k < 8; k++) {
                int f4 = t + k * 256;
                float4 dd = rowp[f4];
                float vals[4] = {dd.x, dd.y, dd.z, dd.w};
                int jb = f4 * 4;
                for (int e = 0; e < 4; e++) {
                    int j = jb + e;
                    bool used = false;
                    for (int q = 0; q < round; q++) used = used || (top8[q] == j);
                    if (!used && vals[e] > bv) { bv = vals[e]; bi = j; }  // ascending j -> ties to lowest
                }
            }
            cand_v[t] = bv; cand_i[t] = bi;
            __syncthreads();
            if (t < 64) {
                for (int c = t + 64; c < 256; c += 64) {
                    float vv = cand_v[c]; int ii = cand_i[c];
                    if (vv > bv || (vv == bv && ii < bi)) { bv = vv; bi = ii; }
                }
#pragma unroll
                for (int s = 32; s > 0; s >>= 1) {
                    float ov = __shfl_down(bv, s);
                    int   oi = __shfl_down(bi, s);
                    if (ov > bv || (ov == bv && oi < bi)) { bv = ov; bi = oi; }
                }
                if (t == 0) top8[round] = bi;
            }
            __syncthreads();
        }
    }
    __syncthreads();

    // epilogue (t0): count, partial, rand_idx, and <=8 scattered mask fixups
    if (t == 0) {
        int r[KSEL];
#pragma unroll
        for (int q = 0; q < KSEL; q++) r[q] = top8[q];
        int c;
        if (full) c = SDIM;
        else {
            c = (whi - wlo + 1) + (wlo < GTOK ? wlo : GTOK);
#pragma unroll
            for (int q = 0; q < KSEL; q++)
                if (r[q] >= GTOK && (r[q] < wlo || r[q] > whi)) c++;
        }
        counts[row] = c;
        cnt_out[row] = (float)c;
        atomicAdd(&partials[row >> 6], c);
#pragma unroll
        for (int q = 0; q < KSEL; q++) {
            rand_idx[row * KSEL + q] = r[q];
            mask_out[(size_t)row * SDIM + r[q]] = 1.0f;   // idempotent if already 1
        }
    }
}

// ---- kernel B: per-row offset from group partials + in-group counts (L2-hot),
// then offsets/cols/sparsity
__global__ __launch_bounds__(256) void col_kernel(const int* __restrict__ rand_idx,
                                                  const int* __restrict__ counts,
                                                  const int* __restrict__ partials,
                                                  float* __restrict__ off_out,
                                                  float* __restrict__ col_out,
                                                  float* __restrict__ sp_out) {
    __shared__ int cs[256];
    __shared__ int s_off;
    const int row = blockIdx.x;
    const int t   = threadIdx.x;

    // offset = sum(partials[0..g-1]) + sum(counts[g*64..row-1])
    if (t < 64) {
        const int g = row >> 6;
        int acc = 0;
        for (int h = t; h < g; h += 64) acc += partials[h];
        for (int i = (g << 6) + t; i < row; i += 64) acc += counts[i];
#pragma unroll
        for (int s = 32; s > 0; s >>= 1) acc += __shfl_down(acc, s);
        if (t == 0) s_off = acc;
    }
    __syncthreads();
    const int offset = s_off;

    int r[KSEL];
#pragma unroll
    for (int q = 0; q < KSEL; q++) r[q] = rand_idx[row * KSEL + q];
    const bool full = row < GTOK;
    int wlo = row - RAD; if (wlo < 0) wlo = 0;
    int whi = row + RAD; if (whi > SDIM - 1) whi = SDIM - 1;

    const int jb = t * 32;
    unsigned int bm;
    if (full || jb + 31 < GTOK) {
        bm = ~0u;
    } else {
        bm = 0u;
        int lo = wlo > jb ? wlo : jb;
        int hi = whi < jb + 31 ? whi : jb + 31;
        if (lo <= hi) {
            int a = lo - jb, z = hi - jb;
            unsigned hiM = (z == 31) ? ~0u : ((1u << (z + 1)) - 1u);
            unsigned loM = (1u << a) - 1u;
            bm = hiM & ~loM;
        }
#pragma unroll
        for (int q = 0; q < KSEL; q++)
            if ((r[q] >> 5) == t) bm |= 1u << (r[q] & 31);
    }
    cs[t] = __popc(bm);
    __syncthreads();
    for (int d = 1; d < 256; d <<= 1) {
        int add = (t >= d) ? cs[t - d] : 0;
        __syncthreads();
        cs[t] += add;
        __syncthreads();
    }
    int pos = offset + ((t == 0) ? 0 : cs[t - 1]);
    for (int e = 0; e < 32; e++) {
        if ((bm >> e) & 1u) col_out[pos++] = (float)(jb + e);
    }

    if (t == 0) {
        off_out[row] = (float)offset;
        if (row == SDIM - 1) {
            int total = offset + counts[row];
            off_out[SDIM] = (float)total;
            sp_out[0] = (float)total / 67108864.0f;   // < 2^24 -> exact
        }
    }
}

extern "C" void kernel_launch(void* const* d_in, const int* in_sizes, int n_in,
                              void* d_out, int out_size, void* d_ws, size_t ws_size,
                              hipStream_t stream) {
    const float* scores = (const float*)d_in[1];   // rand_scores [S,S] f32

    float* out_f    = (float*)d_out;
    float* mask_out = out_f;                                   // S*S
    float* off_out  = out_f + (size_t)SDIM * SDIM;             // S+1
    float* col_out  = off_out + (SDIM + 1);                    // TC
    const long long TC = (long long)out_size
                       - ((long long)SDIM * SDIM + (SDIM + 1) + SDIM + 1);
    float* cnt_out = col_out + TC;                             // S
    float* sp_out  = cnt_out + SDIM;                           // 1

    int* rand_idx = (int*)d_ws;                  // S*K ints
    int* counts   = rand_idx + SDIM * KSEL;      // S ints
    int* partials = counts + SDIM;               // 128 ints

    // ws is NOT re-poisoned between replays -> reset group partials every call
    hipMemsetAsync(partials, 0, 128 * sizeof(int), stream);
    pass1_kernel<<<SDIM, 256, 0, stream>>>(scores, rand_idx, counts, partials,
                                           cnt_out, mask_out);
    col_kernel<<<SDIM, 256, 0, stream>>>(rand_idx, counts, partials,
                                         off_out, col_out, sp_out);
}